// Round 9
// baseline (69.565 us; speedup 1.0000x reference)
//
#include <hip/hip_runtime.h>
#include <stdint.h>

// QuantConv1D (binary, K=3, Cin=128, Cout=256, VALID) + bias + BN(inference)
// via i8 MFMA: out[m=(b,t)][co] = dot * inv[co] + Cb[co], where
// dot = sum_{tap,cin} sign(x[b,t+tap,cin]) * sign(ker[tap,cin,co])  (exact i32),
// inv = rsqrt(var+eps), Cb = (bias-mean)*inv + beta.
//
// R9: MFMA rewrite (G10). GEMM M=64*2046, N=256, K=384 via
// v_mfma_i32_32x32x16_i8. Block = 512 thr = 64 rows x 256 couts:
//  - stage 66 x-rows as sign-i8 in LDS, XOR-swizzled ((row&7)<<4 on byte
//    offset) so b64 fragment reads are <=4-way bank conflicted (G4/T2).
//  - wave w owns couts w*32..+31; B-frags (24 x i64 = 48 VGPR) loaded once
//    from co-major packed weights; 48 MFMA/wave on the matrix pipe.
//  - epilogue: C/D layout col=lane&31, row=(reg&3)+8*(reg>>2)+4*(lane>>5)
//    (HW-verified m74/m101); cvt+fma+NT dword stores (2x128B per instr).

#define B 64
#define T 2048
#define CIN 128
#define COUT 256
#define KW 3
#define TOUT (T - KW + 1)        // 2046
#define MROWS 64                 // output rows per block
#define AROWS (MROWS + KW - 1)   // 66 staged x-rows
#define NBLK_T 32                // t-windows per batch (last overlaps: t0=1982)

typedef int i32x16 __attribute__((ext_vector_type(16)));

// ---- pack kernel signs (i8, co-major) + fold BN affine ----
// kb8[co*384 + tap*128 + cin] = sign i8 (+1 / 0xFF)
__global__ __launch_bounds__(256) void pack_w_kernel(const float* __restrict__ ker,
                                                     const float* __restrict__ bias,
                                                     const float* __restrict__ beta,
                                                     const float* __restrict__ mean,
                                                     const float* __restrict__ var,
                                                     uint8_t* __restrict__ kb8,
                                                     float* __restrict__ Ainv,
                                                     float* __restrict__ Cb) {
    const int tap = blockIdx.x >> 2;    // 0..2
    const int q   = blockIdx.x & 3;     // cin quarter
    const int co  = threadIdx.x;        // 0..255
    #pragma unroll
    for (int j = 0; j < 8; ++j) {
        int cin0 = q * 32 + j * 4;
        const float* s = ker + ((size_t)(tap * CIN + cin0)) * COUT + co;
        uint32_t w = (s[0]               >= 0.f ? 0x01u : 0xFFu)
                   | ((s[(size_t)COUT]     >= 0.f ? 0x01u : 0xFFu) << 8)
                   | ((s[(size_t)2 * COUT] >= 0.f ? 0x01u : 0xFFu) << 16)
                   | ((s[(size_t)3 * COUT] >= 0.f ? 0x01u : 0xFFu) << 24);
        *(uint32_t*)(kb8 + (size_t)co * 384 + tap * 128 + cin0) = w;
    }
    if (blockIdx.x == 0) {
        float inv = 1.0f / sqrtf(var[co] + 1e-3f);
        Ainv[co] = inv;
        Cb[co]   = (bias[co] - mean[co]) * inv + beta[co];
    }
}

// ---- fused stage + MFMA conv + epilogue ----
__global__ __launch_bounds__(512) void conv_mfma_kernel(const float* __restrict__ x,
                                                        const uint8_t* __restrict__ kb8,
                                                        const float* __restrict__ Ainv,
                                                        const float* __restrict__ Cb,
                                                        float* __restrict__ out) {
    const int tid = threadIdx.x;
    const int l   = tid & 63;
    const int wv  = tid >> 6;            // 0..7
    const int bb  = blockIdx.x >> 5;     // batch
    const int wi  = blockIdx.x & 31;     // t-window
    const int t0  = (wi < NBLK_T - 1) ? wi * MROWS : (TOUT - MROWS);  // 1982 last

    __shared__ uint32_t As[AROWS * 32];  // 66 rows x 128B sign-i8, swizzled

    // --- stage: x f32 -> sign-i8 LDS (coalesced float4; 2 rows per wave-read) ---
    {
        const float* xb = x + ((size_t)bb * T + t0) * CIN;
        for (int idx = tid; idx < AROWS * 32; idx += 512) {
            int row = idx >> 5, c4 = idx & 31;
            const float4 v = *(const float4*)(xb + (size_t)row * CIN + c4 * 4);
            uint32_t w = (v.x >= 0.f ? 0x01u : 0xFFu)
                       | ((v.y >= 0.f ? 0x01u : 0xFFu) << 8)
                       | ((v.z >= 0.f ? 0x01u : 0xFFu) << 16)
                       | ((v.w >= 0.f ? 0x01u : 0xFFu) << 24);
            // physical dword col = c4 ^ ((row&7)<<2)  (byte XOR ((row&7)<<4))
            As[row * 32 + (c4 ^ ((row & 7) << 2))] = w;
        }
    }

    // --- B fragments: this wave's 32 couts, all 24 K16-steps (48 VGPR) ---
    const int col = (wv << 5) + (l & 31);     // cout of this lane
    const int kh  = (l >> 5) << 3;            // k-half byte offset: 0 or 8
    long Bf[24];
    {
        const uint8_t* bp = kb8 + (size_t)col * 384 + kh;
        #pragma unroll
        for (int a = 0; a < 24; ++a)
            Bf[a] = *(const long*)(bp + a * 16);
    }
    const float ainv = Ainv[col];
    const float cb   = Cb[col];

    __syncthreads();

    // --- K-loop: 3 taps x 8 K16-steps, 2 M-tiles (rows t0+0..31, t0+32..63) ---
    i32x16 acc0 = {}, acc1 = {};
    const char* Ab = (const char*)As;
    #pragma unroll
    for (int tap = 0; tap < KW; ++tap) {
        #pragma unroll
        for (int s = 0; s < 8; ++s) {
            const int off = s * 16 + kh;
            const int r0 = (l & 31) + tap;
            long A0 = *(const long*)(Ab + r0 * 128 + (off ^ ((r0 & 7) << 4)));
            acc0 = __builtin_amdgcn_mfma_i32_32x32x16_i8(A0, Bf[tap * 8 + s], acc0, 0, 0, 0);
            const int r1 = r0 + 32;
            long A1 = *(const long*)(Ab + r1 * 128 + (off ^ ((r1 & 7) << 4)));
            acc1 = __builtin_amdgcn_mfma_i32_32x32x16_i8(A1, Bf[tap * 8 + s], acc1, 0, 0, 0);
        }
    }

    // --- epilogue: affine + NT stores (col=lane&31; row per m74/m101 formula) ---
    float* ob = out + ((size_t)bb * TOUT + t0) * COUT + col;
    #pragma unroll
    for (int reg = 0; reg < 16; ++reg) {
        const int row = (reg & 3) + 8 * (reg >> 2) + 4 * (l >> 5);
        float o0 = fmaf((float)acc0[reg], ainv, cb);
        __builtin_nontemporal_store(o0, ob + (size_t)row * COUT);
        float o1 = fmaf((float)acc1[reg], ainv, cb);
        __builtin_nontemporal_store(o1, ob + (size_t)(32 + row) * COUT);
    }
}

extern "C" void kernel_launch(void* const* d_in, const int* in_sizes, int n_in,
                              void* d_out, int out_size, void* d_ws, size_t ws_size,
                              hipStream_t stream) {
    const float* x    = (const float*)d_in[0];
    const float* ker  = (const float*)d_in[1];
    const float* bias = (const float*)d_in[2];
    const float* beta = (const float*)d_in[3];
    const float* mean = (const float*)d_in[4];
    const float* var  = (const float*)d_in[5];
    float* out = (float*)d_out;

    // workspace: kb8 (96 KB) | Ainv (1 KB) | Cb (1 KB)
    uint8_t* kb8  = (uint8_t*)d_ws;
    float*   Ainv = (float*)(kb8 + (size_t)COUT * 384);
    float*   Cb   = Ainv + COUT;

    pack_w_kernel<<<KW * 4, 256, 0, stream>>>(ker, bias, beta, mean, var, kb8, Ainv, Cb);
    conv_mfma_kernel<<<B * NBLK_T, 512, 0, stream>>>(x, kb8, Ainv, Cb, out);
}

// Round 10
// 55.577 us; speedup vs baseline: 1.2517x; 1.2517x over previous
//
#include <hip/hip_runtime.h>
#include <stdint.h>

// QuantConv1D (binary, K=3, Cin=128, Cout=256, VALID) + bias + BN(inference)
// via i8 MFMA: out[m=(b,t)][co] = dot * inv[co] + Cb[co],
// dot = sum_{tap,cin} sign(x[b,t+tap,cin]) * sign(ker[tap,cin,co]) (exact i32).
//
// R10: MFMA v2.
//  - v_mfma_i32_32x32x32_i8 (K=32): 24 MFMA/wave, A-frag = one b128 LDS read.
//  - A staged as sign-i8 rows (128B), 16B-slot XOR swizzle ((row&7)) -> <=4-way.
//  - B-frags: 12 b128 global loads/lane, issued BEFORE staging (latency hide).
//  - Epilogue: 4 chunks x 16 rows through LDS Ct[16][256] f32 transpose
//    (bank = lane&31, conflict-free), then linear float4 NT stores
//    (1KB/wave-instr) -- R6's proven store pattern.
// C/D layout (HW-verified m74/m101): col=lane&31, row=(reg&3)+8*(reg>>2)+4*(lane>>5).

#define B 64
#define T 2048
#define CIN 128
#define COUT 256
#define KW 3
#define TOUT (T - KW + 1)        // 2046
#define MROWS 64                 // output rows per block
#define AROWS (MROWS + KW - 1)   // 66 staged x-rows
#define NBLK_T 32                // t-windows per batch (last overlaps: t0=1982)

typedef int   i32x4  __attribute__((ext_vector_type(4)));
typedef int   i32x16 __attribute__((ext_vector_type(16)));
typedef float f32x4  __attribute__((ext_vector_type(4)));

// ---- pack kernel signs (i8 +1/-1, co-major) + fold BN affine ----
// kb8[co*384 + tap*128 + cin]
__global__ __launch_bounds__(256) void pack_w_kernel(const float* __restrict__ ker,
                                                     const float* __restrict__ bias,
                                                     const float* __restrict__ beta,
                                                     const float* __restrict__ mean,
                                                     const float* __restrict__ var,
                                                     uint8_t* __restrict__ kb8,
                                                     float* __restrict__ Ainv,
                                                     float* __restrict__ Cb) {
    const int tap = blockIdx.x >> 2;    // 0..2
    const int q   = blockIdx.x & 3;     // cin quarter
    const int co  = threadIdx.x;        // 0..255
    #pragma unroll
    for (int j = 0; j < 8; ++j) {
        int cin0 = q * 32 + j * 4;
        const float* s = ker + ((size_t)(tap * CIN + cin0)) * COUT + co;
        uint32_t w = (s[0]                >= 0.f ? 0x01u : 0xFFu)
                   | ((s[(size_t)COUT]     >= 0.f ? 0x01u : 0xFFu) << 8)
                   | ((s[(size_t)2 * COUT] >= 0.f ? 0x01u : 0xFFu) << 16)
                   | ((s[(size_t)3 * COUT] >= 0.f ? 0x01u : 0xFFu) << 24);
        *(uint32_t*)(kb8 + (size_t)co * 384 + tap * 128 + cin0) = w;
    }
    if (blockIdx.x == 0) {
        float inv = 1.0f / sqrtf(var[co] + 1e-3f);
        Ainv[co] = inv;
        Cb[co]   = (bias[co] - mean[co]) * inv + beta[co];
    }
}

// ---- fused stage + MFMA conv + transposed epilogue ----
__global__ __launch_bounds__(512) void conv_mfma_kernel(const float* __restrict__ x,
                                                        const uint8_t* __restrict__ kb8,
                                                        const float* __restrict__ Ainv,
                                                        const float* __restrict__ Cb,
                                                        float* __restrict__ out) {
    const int tid = threadIdx.x;
    const int l   = tid & 63;
    const int wv  = tid >> 6;            // 0..7
    const int bb  = blockIdx.x >> 5;     // batch
    const int wi  = blockIdx.x & 31;     // t-window
    const int t0  = (wi < NBLK_T - 1) ? wi * MROWS : (TOUT - MROWS);  // 1982 last

    __shared__ uint32_t As[AROWS * 32];  // 66 rows x 128B sign-i8, 16B-slot swizzle
    __shared__ float    Ct[16 * 256];    // epilogue transpose buffer (16KB)

    // --- B fragments first (long-latency, hidden under staging) ---
    // lane covers col = wv*32+(l&31); k-half bytes kh = (l>>5)*16 of each 32.
    const int col = (wv << 5) + (l & 31);
    const int kh  = (l >> 5) << 4;
    i32x4 Bf[12];
    {
        const uint8_t* bp = kb8 + (size_t)col * 384 + kh;
        #pragma unroll
        for (int a = 0; a < 12; ++a)
            Bf[a] = *(const i32x4*)(bp + a * 32);
    }
    const float ainv = Ainv[col];
    const float cb   = Cb[col];

    // --- stage x -> sign-i8 LDS (coalesced float4 reads) ---
    {
        const float* xb = x + ((size_t)bb * T + t0) * CIN;
        for (int idx = tid; idx < AROWS * 32; idx += 512) {
            int row = idx >> 5, c4 = idx & 31;
            const float4 v = *(const float4*)(xb + (size_t)row * CIN + c4 * 4);
            uint32_t w = (v.x >= 0.f ? 0x01u : 0xFFu)
                       | ((v.y >= 0.f ? 0x01u : 0xFFu) << 8)
                       | ((v.z >= 0.f ? 0x01u : 0xFFu) << 16)
                       | ((v.w >= 0.f ? 0x01u : 0xFFu) << 24);
            int slot = (c4 >> 2) ^ (row & 7);            // 16B-slot swizzle
            As[row * 32 + slot * 4 + (c4 & 3)] = w;
        }
    }
    __syncthreads();

    // --- K-loop: 3 taps x 4 K32-steps x 2 M-tiles = 24 MFMA ---
    i32x16 acc0 = {}, acc1 = {};
    const char* Ab = (const char*)As;
    #pragma unroll
    for (int tap = 0; tap < KW; ++tap) {
        #pragma unroll
        for (int s = 0; s < 4; ++s) {
            const int slot = s * 2 + (l >> 5);           // logical 16B slot
            const i32x4 bf = Bf[tap * 4 + s];
            const int r0 = (l & 31) + tap;
            i32x4 A0 = *(const i32x4*)(Ab + r0 * 128 + ((slot ^ (r0 & 7)) << 4));
            acc0 = __builtin_amdgcn_mfma_i32_32x32x32_i8(A0, bf, acc0, 0, 0, 0);
            const int r1 = r0 + 32;
            i32x4 A1 = *(const i32x4*)(Ab + r1 * 128 + ((slot ^ (r1 & 7)) << 4));
            acc1 = __builtin_amdgcn_mfma_i32_32x32x32_i8(A1, bf, acc1, 0, 0, 0);
        }
    }

    // --- epilogue: 4 chunks x 16 rows; LDS transpose -> linear NT float4 ---
    float* ob = out + ((size_t)bb * TOUT + t0) * COUT;
    #pragma unroll
    for (int ch = 0; ch < 4; ++ch) {
        // rows ch*16 .. ch*16+15 come from acc(ch>>1), regs (ch&1)*8 .. +7
        #pragma unroll
        for (int rr = 0; rr < 8; ++rr) {
            const int reg  = rr + (ch & 1) * 8;
            const int row16 = (rr & 3) + 8 * (rr >> 2) + 4 * (l >> 5);
            const int a = (ch >> 1) ? acc1[reg] : acc0[reg];
            Ct[row16 * 256 + col] = fmaf((float)a, ainv, cb);
        }
        __syncthreads();
        #pragma unroll
        for (int it = 0; it < 2; ++it) {
            const int idx  = tid + it * 512;      // 0..1023
            const int row16 = idx >> 6;
            const int cc    = idx & 63;
            f32x4 vv = *(const f32x4*)(Ct + row16 * 256 + cc * 4);
            __builtin_nontemporal_store(
                vv, (f32x4*)(ob + (size_t)(ch * 16 + row16) * COUT + cc * 4));
        }
        __syncthreads();
    }
}

extern "C" void kernel_launch(void* const* d_in, const int* in_sizes, int n_in,
                              void* d_out, int out_size, void* d_ws, size_t ws_size,
                              hipStream_t stream) {
    const float* x    = (const float*)d_in[0];
    const float* ker  = (const float*)d_in[1];
    const float* bias = (const float*)d_in[2];
    const float* beta = (const float*)d_in[3];
    const float* mean = (const float*)d_in[4];
    const float* var  = (const float*)d_in[5];
    float* out = (float*)d_out;

    // workspace: kb8 (96 KB) | Ainv (1 KB) | Cb (1 KB)
    uint8_t* kb8  = (uint8_t*)d_ws;
    float*   Ainv = (float*)(kb8 + (size_t)COUT * 384);
    float*   Cb   = Ainv + COUT;

    pack_w_kernel<<<KW * 4, 256, 0, stream>>>(ker, bias, beta, mean, var, kb8, Ainv, Cb);
    conv_mfma_kernel<<<B * NBLK_T, 512, 0, stream>>>(x, kb8, Ainv, Cb, out);
}